// Round 1
// baseline (181.854 us; speedup 1.0000x reference)
//
#include <hip/hip_runtime.h>
#include <hip/hip_cooperative_groups.h>

namespace cg = cooperative_groups;

#define N 4096
#define F 64
#define BZ 4
#define NC 65            // 64 features + 1 denominator component
// hierarchy: 64 superchunks x 16 subchunks x 4 rows = 4096 sorted rows

// order-preserving float <-> uint32 mapping
__device__ __forceinline__ unsigned int f2ord(float f) {
    unsigned int u = __float_as_uint(f);
    return (u & 0x80000000u) ? ~u : (u ^ 0x80000000u);
}
__device__ __forceinline__ float ord2f(unsigned int v) {
    unsigned int b = (v & 0x80000000u) ? (v ^ 0x80000000u) : ~v;
    return __uint_as_float(b);
}

// ===========================================================================
// FUSED cooperative kernel: all 4 phases in one dispatch, grid 256 x 1024
// (1 block/CU, exactly co-resident). LDS is a 51 KB union across phases.
//   smem layout P1: qs u64[4096] @0 (32768) | pc u16[16][64] @32768 | rs @34816
//               P2: l1 f32[16][66] @0 | l2 @4224
//               P3: sS1 f32[64][66] @0 | sS2 @16896 | tile @33792 (16640)
//                   | pA @50432 | kkA @50688   -> 50944 B total
// ===========================================================================
__global__ __launch_bounds__(1024) void fused_gat(
        const float* __restrict__ x, const float* __restrict__ wk,
        const float* __restrict__ wq, float* __restrict__ karr,
        unsigned long long* __restrict__ qkey, float* __restrict__ q_sorted,
        float* __restrict__ sub1, float* __restrict__ sub2,
        float* __restrict__ sup1, float* __restrict__ sup2,
        float* __restrict__ xs, float* __restrict__ out) {
    __shared__ __align__(16) char smem[50944];
    cg::grid_group gg = cg::this_grid();

    const int bid  = blockIdx.x;
    const int tid  = threadIdx.x;
    const int wave = tid >> 6, lane = tid & 63;
    const int b    = bid >> 6;

    // ---- Phase 0 (was kq_kernel): k = x.wk, qkey = (ord(x.wq)<<32)|j ------
    // 4096 waves x 4 rows each; lane l: row lg=l>>4, feature quad (l&15)*4.
    {
        int gw  = bid * 16 + wave;           // 0..4095
        int row = gw * 4 + (lane >> 4);      // 0..16383
        int f0  = (lane & 15) * 4;
        float4 xv = *(const float4*)(x + (size_t)row * F + f0);
        float4 k4 = *(const float4*)(wk + f0);
        float4 q4 = *(const float4*)(wq + f0);
        float kk = xv.x * k4.x + xv.y * k4.y + xv.z * k4.z + xv.w * k4.w;
        float qq = xv.x * q4.x + xv.y * q4.y + xv.z * q4.z + xv.w * q4.w;
#pragma unroll
        for (int off = 1; off <= 8; off <<= 1) {
            kk += __shfl_xor(kk, off, 16);
            qq += __shfl_xor(qq, off, 16);
        }
        if ((lane & 15) == 0) {
            karr[row] = kk;
            qkey[row] = ((unsigned long long)f2ord(qq) << 32)
                      | (unsigned int)(row & (N - 1));
        }
    }
    gg.sync();

    // ---- Phase 1 (was rank_kernel): counting rank-sort + x permutation ----
    {
        unsigned long long* qs = (unsigned long long*)smem;
        unsigned short (*pc)[64] = (unsigned short(*)[64])(smem + 32768);
        unsigned short* rs = (unsigned short*)(smem + 34816);
        const unsigned long long* qb = qkey + b * N;
        for (int t = tid; t < N; t += 1024) qs[t] = qb[t];
        __syncthreads();

        int jbase = (bid & 63) * 64;
        int j = jbase + lane;
        unsigned long long myKey = qs[j];
        int cnt = 0;
        const ulonglong2* q2 = (const ulonglong2*)qs;
        int s0 = wave * 128;                  // ulonglong2 units
#pragma unroll 8
        for (int t2 = 0; t2 < 128; ++t2) {
            ulonglong2 v = q2[s0 + t2];
            cnt += (int)(v.x < myKey) + (int)(v.y < myKey);
        }
        pc[wave][lane] = (unsigned short)cnt;
        __syncthreads();

        if (wave == 0) {
            int r = 0;
#pragma unroll
            for (int pp = 0; pp < 16; ++pp) r += pc[pp][lane];
            q_sorted[b * N + r] = ord2f((unsigned int)(myKey >> 32));
            rs[lane] = (unsigned short)r;
        }
        __syncthreads();

#pragma unroll
        for (int s = 0; s < 4; ++s) {
            int jl = wave * 4 + s;
            int r = rs[jl];
            xs[((size_t)(b * N + r)) * F + lane] =
                x[((size_t)(b * N + jbase + jl)) * F + lane];
        }
    }
    gg.sync();

    // ---- Phase 2 (was chunkscan_kernel) -----------------------------------
    {
        float (*l1)[66] = (float(*)[66])smem;
        float (*l2)[66] = (float(*)[66])(smem + 4224);
        int sp = bid & 63;
        const float* qsb = q_sorted + b * N;
        float Qmax = qsb[N - 1];
        int base = sp * 64 + wave * 4;
        float a1 = 0.f, a2 = 0.f, s1 = 0.f, s2 = 0.f;
#pragma unroll
        for (int r = 0; r < 4; ++r) {
            int t = base + r;
            float d = qsb[t] - Qmax;
            float e1 = __expf(d);
            float e2 = __expf(0.2f * d);
            float xv = xs[((size_t)(b * N + t)) * F + lane];
            a1 += e1 * xv; s1 += e1;
            a2 += e2 * xv; s2 += e2;
        }
        l1[wave][lane] = a1; l2[wave][lane] = a2;
        if (lane == 0) { l1[wave][64] = s1; l2[wave][64] = s2; }
        __syncthreads();

        float suf = 0.f, sufd = 0.f;
        for (int u = wave + 1; u < 16; ++u) { suf += l1[u][lane]; sufd += l1[u][64]; }
        float pre = 0.f, pred = 0.f;
        for (int u = 0; u < wave; ++u) { pre += l2[u][lane]; pred += l2[u][64]; }

        size_t srow = ((size_t)((b * 64 + sp) * 16 + wave)) * NC;
        sub1[srow + lane] = suf;
        sub2[srow + lane] = pre;
        if (lane == 0) { sub1[srow + 64] = sufd; sub2[srow + 64] = pred; }

        size_t prow = ((size_t)(b * 64 + sp)) * NC;
        if (wave == 0) {
            sup1[prow + lane] = suf + a1;
            if (lane == 0) sup1[prow + 64] = sufd + s1;
        }
        if (wave == 15) {
            sup2[prow + lane] = pre + a2;
            if (lane == 0) sup2[prow + 64] = pred + s2;
        }
    }
    gg.sync();

    // ---- Phase 3 (was out_kernel) -----------------------------------------
    {
        float (*sS1)[66] = (float(*)[66])smem;
        float (*sS2)[66] = (float(*)[66])(smem + 16896);
        float* tile = (float*)(smem + 33792);
        int* pA   = (int*)(smem + 50432);
        float* kkA = (float*)(smem + 50688);
        int i0 = (bid & 63) * 64;
        const float* qsb = q_sorted + b * N;
        float Qmax = qsb[N - 1];

        for (int s = wave; s < 64; s += 16) {
            size_t prow = ((size_t)(b * 64 + s)) * NC;
            sS1[s][lane] = sup1[prow + lane];
            sS2[s][lane] = sup2[prow + lane];
            if (lane == 0) { sS1[s][64] = sup1[prow + 64]; sS2[s][64] = sup2[prow + 64]; }
        }
        __syncthreads();
        if (tid < 65) {
            int comp = tid;
            float g0 = 0.f, g1 = 0.f, g2 = 0.f, g3 = 0.f;
#pragma unroll
            for (int e = 0; e < 16; ++e) {
                g0 += sS1[e][comp];      g1 += sS1[16 + e][comp];
                g2 += sS1[32 + e][comp]; g3 += sS1[48 + e][comp];
            }
            float r0 = g1 + g2 + g3, r1 = g2 + g3, r2 = g3, r3 = 0.f;
            (void)g0;
#pragma unroll
            for (int e = 15; e >= 0; --e) {
                float v0 = sS1[e][comp],      v1 = sS1[16 + e][comp];
                float v2 = sS1[32 + e][comp], v3 = sS1[48 + e][comp];
                sS1[e][comp] = r0;      r0 += v0;
                sS1[16 + e][comp] = r1; r1 += v1;
                sS1[32 + e][comp] = r2; r2 += v2;
                sS1[48 + e][comp] = r3; r3 += v3;
            }
        } else if (tid < 130) {
            int comp = tid - 65;
            float g0 = 0.f, g1 = 0.f, g2 = 0.f, g3 = 0.f;
#pragma unroll
            for (int e = 0; e < 16; ++e) {
                g0 += sS2[e][comp];      g1 += sS2[16 + e][comp];
                g2 += sS2[32 + e][comp]; g3 += sS2[48 + e][comp];
            }
            float r0 = 0.f, r1 = g0, r2 = g0 + g1, r3 = g0 + g1 + g2;
#pragma unroll
            for (int e = 0; e < 16; ++e) {
                float v0 = sS2[e][comp],      v1 = sS2[16 + e][comp];
                float v2 = sS2[32 + e][comp], v3 = sS2[48 + e][comp];
                sS2[e][comp] = r0;      r0 += v0;
                sS2[16 + e][comp] = r1; r1 += v1;
                sS2[32 + e][comp] = r2; r2 += v2;
                sS2[48 + e][comp] = r3; r3 += v3;
            }
        } else if (tid < 194) {
            int il = tid - 130;
            float kk = karr[b * N + i0 + il];
            float theta = -kk;
            int lo = 0, hi = N;
#pragma unroll
            for (int step = 0; step < 12; ++step) {
                int mid = (lo + hi) >> 1;
                if (qsb[mid] < theta) lo = mid + 1; else hi = mid;
            }
            pA[il] = lo;
            kkA[il] = kk;
        }
        __syncthreads();

#pragma unroll
        for (int s = 0; s < 4; ++s) {
            int il = wave * 4 + s;
            float kk = kkA[il];
            int p = pA[il];
            int c = p >> 2; if (c > 1023) c = 1023;
            int sp = c >> 4, su = c & 15;
            int r0 = p - (c << 2);
            float u = kk + Qmax;
            float M = fmaxf(u, 0.2f * u);
            float c1 = __expf(u - M);
            float c2 = __expf(0.2f * u - M);
            size_t srow = ((size_t)((b * 64 + sp) * 16 + su)) * NC;
            float a1 = sS1[sp][lane] + sub1[srow + lane];
            float s1 = sS1[sp][64] + sub1[srow + 64];
            float a2 = sS2[sp][lane] + sub2[srow + lane];
            float s2 = sS2[sp][64] + sub2[srow + 64];
            int tb = c << 2;
#pragma unroll
            for (int r = 0; r < 4; ++r) {
                float d = qsb[tb + r] - Qmax;
                float xv = xs[((size_t)(b * N + tb + r)) * F + lane];
                if (r >= r0) { float e1 = __expf(d);        a1 += e1 * xv; s1 += e1; }
                else         { float e2 = __expf(0.2f * d); a2 += e2 * xv; s2 += e2; }
            }
            float num = c1 * a1 + c2 * a2;
            float den = c1 * s1 + c2 * s2;
            tile[lane * 65 + il] = num / den;
        }
        __syncthreads();
#pragma unroll
        for (int rep = 0; rep < 4; ++rep) {
            int ff = rep * 16 + wave;
            out[((size_t)(b * F + ff)) * N + i0 + lane] = tile[ff * 65 + lane];
        }
    }
}

// ===========================================================================
// Fallback path: original 4-kernel pipeline (used only if cooperative launch
// is rejected, e.g. graph-capture incompatibility).
// ===========================================================================
__global__ __launch_bounds__(256) void kq_kernel(
        const float* __restrict__ x, const float* __restrict__ wk,
        const float* __restrict__ wq, float* __restrict__ karr,
        unsigned long long* __restrict__ qkey) {
    int wave = blockIdx.x * 4 + (threadIdx.x >> 6);
    int lane = threadIdx.x & 63;
    int row = wave;
    float xv = x[(size_t)row * F + lane];
    float kk = xv * wk[lane];
    float qq = xv * wq[lane];
    for (int off = 32; off > 0; off >>= 1) {
        kk += __shfl_down(kk, off, 64);
        qq += __shfl_down(qq, off, 64);
    }
    if (lane == 0) {
        karr[row] = kk;
        qkey[row] = ((unsigned long long)f2ord(qq) << 32)
                  | (unsigned int)(row & (N - 1));
    }
}

__global__ __launch_bounds__(1024) void rank_kernel(
        const float* __restrict__ x,
        const unsigned long long* __restrict__ qkey,
        float* __restrict__ q_sorted, float* __restrict__ xs) {
    __shared__ __align__(16) unsigned long long qs[N];
    __shared__ unsigned short pc[16][64];
    __shared__ unsigned short rs[64];
    int b = blockIdx.x >> 6;
    int tid = threadIdx.x;
    int wave = tid >> 6, lane = tid & 63;
    const unsigned long long* qb = qkey + b * N;
    for (int t = tid; t < N; t += 1024) qs[t] = qb[t];
    __syncthreads();

    int jbase = (blockIdx.x & 63) * 64;
    int j = jbase + lane;
    unsigned long long myKey = qs[j];
    int cnt = 0;
    const ulonglong2* q2 = (const ulonglong2*)qs;
    int s0 = wave * 128;
#pragma unroll 8
    for (int t2 = 0; t2 < 128; ++t2) {
        ulonglong2 v = q2[s0 + t2];
        cnt += (int)(v.x < myKey) + (int)(v.y < myKey);
    }
    pc[wave][lane] = (unsigned short)cnt;
    __syncthreads();

    if (wave == 0) {
        int r = 0;
#pragma unroll
        for (int pp = 0; pp < 16; ++pp) r += pc[pp][lane];
        q_sorted[b * N + r] = ord2f((unsigned int)(myKey >> 32));
        rs[lane] = (unsigned short)r;
    }
    __syncthreads();

#pragma unroll
    for (int s = 0; s < 4; ++s) {
        int jl = wave * 4 + s;
        int r = rs[jl];
        xs[((size_t)(b * N + r)) * F + lane] =
            x[((size_t)(b * N + jbase + jl)) * F + lane];
    }
}

__global__ __launch_bounds__(1024) void chunkscan_kernel(
        const float* __restrict__ xs, const float* __restrict__ q_sorted,
        float* __restrict__ sub1, float* __restrict__ sub2,
        float* __restrict__ sup1, float* __restrict__ sup2) {
    __shared__ float l1[16][66], l2[16][66];
    int b = blockIdx.x >> 6;
    int sp = blockIdx.x & 63;
    int w = threadIdx.x >> 6, lane = threadIdx.x & 63;
    const float* qsb = q_sorted + b * N;
    float Qmax = qsb[N - 1];
    int base = sp * 64 + w * 4;
    float a1 = 0.f, a2 = 0.f, s1 = 0.f, s2 = 0.f;
#pragma unroll
    for (int r = 0; r < 4; ++r) {
        int t = base + r;
        float d = qsb[t] - Qmax;
        float e1 = __expf(d);
        float e2 = __expf(0.2f * d);
        float xv = xs[((size_t)(b * N + t)) * F + lane];
        a1 += e1 * xv; s1 += e1;
        a2 += e2 * xv; s2 += e2;
    }
    l1[w][lane] = a1; l2[w][lane] = a2;
    if (lane == 0) { l1[w][64] = s1; l2[w][64] = s2; }
    __syncthreads();

    float suf = 0.f, sufd = 0.f;
    for (int u = w + 1; u < 16; ++u) { suf += l1[u][lane]; sufd += l1[u][64]; }
    float pre = 0.f, pred = 0.f;
    for (int u = 0; u < w; ++u) { pre += l2[u][lane]; pred += l2[u][64]; }

    size_t srow = ((size_t)((b * 64 + sp) * 16 + w)) * NC;
    sub1[srow + lane] = suf;
    sub2[srow + lane] = pre;
    if (lane == 0) { sub1[srow + 64] = sufd; sub2[srow + 64] = pred; }

    size_t prow = ((size_t)(b * 64 + sp)) * NC;
    if (w == 0) {
        sup1[prow + lane] = suf + a1;
        if (lane == 0) sup1[prow + 64] = sufd + s1;
    }
    if (w == 15) {
        sup2[prow + lane] = pre + a2;
        if (lane == 0) sup2[prow + 64] = pred + s2;
    }
}

__global__ __launch_bounds__(1024) void out_kernel(
        const float* __restrict__ karr, const float* __restrict__ q_sorted,
        const float* __restrict__ sub1, const float* __restrict__ sub2,
        const float* __restrict__ sup1, const float* __restrict__ sup2,
        const float* __restrict__ xs, float* __restrict__ out) {
    __shared__ float sS1[64][66], sS2[64][66];
    __shared__ float tile[64 * 65];
    __shared__ int pA[64];
    __shared__ float kkA[64];
    int b = blockIdx.x >> 6;
    int i0 = (blockIdx.x & 63) * 64;
    int tid = threadIdx.x;
    int wave = tid >> 6, lane = tid & 63;
    const float* qsb = q_sorted + b * N;
    float Qmax = qsb[N - 1];

    for (int s = wave; s < 64; s += 16) {
        size_t prow = ((size_t)(b * 64 + s)) * NC;
        sS1[s][lane] = sup1[prow + lane];
        sS2[s][lane] = sup2[prow + lane];
        if (lane == 0) { sS1[s][64] = sup1[prow + 64]; sS2[s][64] = sup2[prow + 64]; }
    }
    __syncthreads();
    if (tid < 65) {
        int comp = tid;
        float g0 = 0.f, g1 = 0.f, g2 = 0.f, g3 = 0.f;
#pragma unroll
        for (int e = 0; e < 16; ++e) {
            g0 += sS1[e][comp];      g1 += sS1[16 + e][comp];
            g2 += sS1[32 + e][comp]; g3 += sS1[48 + e][comp];
        }
        float r0 = g1 + g2 + g3, r1 = g2 + g3, r2 = g3, r3 = 0.f;
        (void)g0;
#pragma unroll
        for (int e = 15; e >= 0; --e) {
            float v0 = sS1[e][comp],      v1 = sS1[16 + e][comp];
            float v2 = sS1[32 + e][comp], v3 = sS1[48 + e][comp];
            sS1[e][comp] = r0;      r0 += v0;
            sS1[16 + e][comp] = r1; r1 += v1;
            sS1[32 + e][comp] = r2; r2 += v2;
            sS1[48 + e][comp] = r3; r3 += v3;
        }
    } else if (tid < 130) {
        int comp = tid - 65;
        float g0 = 0.f, g1 = 0.f, g2 = 0.f, g3 = 0.f;
#pragma unroll
        for (int e = 0; e < 16; ++e) {
            g0 += sS2[e][comp];      g1 += sS2[16 + e][comp];
            g2 += sS2[32 + e][comp]; g3 += sS2[48 + e][comp];
        }
        float r0 = 0.f, r1 = g0, r2 = g0 + g1, r3 = g0 + g1 + g2;
#pragma unroll
        for (int e = 0; e < 16; ++e) {
            float v0 = sS2[e][comp],      v1 = sS2[16 + e][comp];
            float v2 = sS2[32 + e][comp], v3 = sS2[48 + e][comp];
            sS2[e][comp] = r0;      r0 += v0;
            sS2[16 + e][comp] = r1; r1 += v1;
            sS2[32 + e][comp] = r2; r2 += v2;
            sS2[48 + e][comp] = r3; r3 += v3;
        }
    } else if (tid < 194) {
        int il = tid - 130;
        float kk = karr[b * N + i0 + il];
        float theta = -kk;
        int lo = 0, hi = N;
#pragma unroll
        for (int step = 0; step < 12; ++step) {
            int mid = (lo + hi) >> 1;
            if (qsb[mid] < theta) lo = mid + 1; else hi = mid;
        }
        pA[il] = lo;
        kkA[il] = kk;
    }
    __syncthreads();

#pragma unroll
    for (int s = 0; s < 4; ++s) {
        int il = wave * 4 + s;
        float kk = kkA[il];
        int p = pA[il];
        int c = p >> 2; if (c > 1023) c = 1023;
        int sp = c >> 4, su = c & 15;
        int r0 = p - (c << 2);
        float u = kk + Qmax;
        float M = fmaxf(u, 0.2f * u);
        float c1 = __expf(u - M);
        float c2 = __expf(0.2f * u - M);
        size_t srow = ((size_t)((b * 64 + sp) * 16 + su)) * NC;
        float a1 = sS1[sp][lane] + sub1[srow + lane];
        float s1 = sS1[sp][64] + sub1[srow + 64];
        float a2 = sS2[sp][lane] + sub2[srow + lane];
        float s2 = sS2[sp][64] + sub2[srow + 64];
        int tb = c << 2;
#pragma unroll
        for (int r = 0; r < 4; ++r) {
            float d = qsb[tb + r] - Qmax;
            float xv = xs[((size_t)(b * N + tb + r)) * F + lane];
            if (r >= r0) { float e1 = __expf(d);        a1 += e1 * xv; s1 += e1; }
            else         { float e2 = __expf(0.2f * d); a2 += e2 * xv; s2 += e2; }
        }
        float num = c1 * a1 + c2 * a2;
        float den = c1 * s1 + c2 * s2;
        tile[lane * 65 + il] = num / den;
    }
    __syncthreads();
#pragma unroll
    for (int rep = 0; rep < 4; ++rep) {
        int ff = rep * 16 + wave;
        out[((size_t)(b * F + ff)) * N + i0 + lane] = tile[ff * 65 + lane];
    }
}

// ---------------------------------------------------------------------------
extern "C" void kernel_launch(void* const* d_in, const int* in_sizes, int n_in,
                              void* d_out, int out_size, void* d_ws, size_t ws_size,
                              hipStream_t stream) {
    const float* x  = (const float*)d_in[0];
    const float* wk = (const float*)d_in[1];
    const float* wq = (const float*)d_in[2];
    float* out = (float*)d_out;

    // ws layout (floats): karr[BZ*N] | qkey(u64)[BZ*N] (=2*BZ*N floats) |
    //   q_sorted[BZ*N] | sub1[BZ*1024*NC] | sub2[...] | sup1[BZ*64*NC] |
    //   sup2[...] | xs[BZ*N*F]
    float* ws = (float*)d_ws;
    float* karr = ws;
    unsigned long long* qkey = (unsigned long long*)(ws + BZ * N);
    float* q_sorted = ws + 3 * BZ * N;
    float* sub1     = ws + 4 * BZ * N;
    float* sub2     = sub1 + (size_t)BZ * 1024 * NC;
    float* sup1     = sub2 + (size_t)BZ * 1024 * NC;
    float* sup2     = sup1 + (size_t)BZ * 64 * NC;
    float* xs       = sup2 + (size_t)BZ * 64 * NC;

    void* args[] = { (void*)&x, (void*)&wk, (void*)&wq, (void*)&karr,
                     (void*)&qkey, (void*)&q_sorted, (void*)&sub1, (void*)&sub2,
                     (void*)&sup1, (void*)&sup2, (void*)&xs, (void*)&out };
    hipError_t err = hipLaunchCooperativeKernel(
        (const void*)fused_gat, dim3(BZ * 64), dim3(1024), args, 0, stream);
    if (err != hipSuccess) {
        // fallback: original 4-kernel pipeline
        kq_kernel<<<BZ * N / 4, 256, 0, stream>>>(x, wk, wq, karr, qkey);
        rank_kernel<<<BZ * 64, 1024, 0, stream>>>(x, qkey, q_sorted, xs);
        chunkscan_kernel<<<BZ * 64, 1024, 0, stream>>>(xs, q_sorted, sub1, sub2,
                                                       sup1, sup2);
        out_kernel<<<BZ * 64, 1024, 0, stream>>>(karr, q_sorted, sub1, sub2,
                                                 sup1, sup2, xs, out);
    }
}

// Round 3
// 112.280 us; speedup vs baseline: 1.6196x; 1.6196x over previous
//
#include <hip/hip_runtime.h>

#define N 4096
#define F 64
#define BZ 4
// NEG_SLOPE = 0.2 hardcoded below.

// order-preserving float <-> uint32 mapping
__device__ __forceinline__ unsigned int f2ord(float f) {
    unsigned int u = __float_as_uint(f);
    return (u & 0x80000000u) ? ~u : (u ^ 0x80000000u);
}
__device__ __forceinline__ float ord2f(unsigned int v) {
    unsigned int b = (v & 0x80000000u) ? (v ^ 0x80000000u) : ~v;
    return __uint_as_float(b);
}

// ===========================================================================
// K1: grid BZ*64, block 1024. Block = (batch b, chunk of 64 original rows).
// Phase 1: every block computes ALL 4096 q-dots of its batch into LDS keys
//   (u64 = ord(q)<<32 | row). x reads are coalesced float4 and L2-resident
//   (x = 4 MB total). k-dots written to karr only for the block's own chunk.
//   Dot order is identical in every block -> bitwise-identical keys -> ranks
//   are consistent across blocks.
// Phase 2: rank count for the chunk's 64 rows (wave-uniform broadcast LDS
//   reads, 256 keys per wave slice), then scatter:
//     q_sorted[b][r] = q value, ordidx[b][r] = original row.
// ===========================================================================
__global__ __launch_bounds__(1024) void rank_kernel(
        const float* __restrict__ x, const float* __restrict__ wk,
        const float* __restrict__ wq, float* __restrict__ karr,
        float* __restrict__ q_sorted, unsigned int* __restrict__ ordidx) {
    __shared__ __align__(16) unsigned long long qs[N];   // 32 KB
    __shared__ unsigned short pc[16][64];
    const int b = blockIdx.x >> 6, chunk = blockIdx.x & 63;
    const int tid = threadIdx.x;
    const int wave = tid >> 6, lane = tid & 63;
    const int sub = lane >> 4;               // row-in-quad
    const int f0 = (lane & 15) << 2;         // feature quad
    const float4 k4 = *(const float4*)(wk + f0);
    const float4 q4 = *(const float4*)(wq + f0);
    const float* xb = x + (size_t)b * N * F;

    // wave w covers rows [w*256, (w+1)*256), 4 rows per iteration.
#pragma unroll 4
    for (int it = 0; it < 64; ++it) {
        int row = (wave << 8) + (it << 2) + sub;
        float4 xv = *(const float4*)(xb + (size_t)row * F + f0);
        float kk = xv.x * k4.x + xv.y * k4.y + xv.z * k4.z + xv.w * k4.w;
        float qq = xv.x * q4.x + xv.y * q4.y + xv.z * q4.z + xv.w * q4.w;
#pragma unroll
        for (int off = 1; off <= 8; off <<= 1) {
            kk += __shfl_xor(kk, off, 16);
            qq += __shfl_xor(qq, off, 16);
        }
        if ((lane & 15) == 0) {
            qs[row] = ((unsigned long long)f2ord(qq) << 32)
                    | (unsigned int)row;
            if ((row >> 6) == chunk) karr[b * N + row] = kk;
        }
    }
    __syncthreads();

    // rank count: strict total order on distinct u64 keys (row in low bits)
    const int jbase = chunk << 6;
    const unsigned long long myKey = qs[jbase + lane];
    int cnt = 0;
    const ulonglong2* q2 = (const ulonglong2*)qs;
    const int s0 = wave * 128;                // ulonglong2 units
#pragma unroll 8
    for (int t2 = 0; t2 < 128; ++t2) {
        ulonglong2 v = q2[s0 + t2];           // wave-uniform broadcast read
        cnt += (int)(v.x < myKey) + (int)(v.y < myKey);
    }
    pc[wave][lane] = (unsigned short)cnt;
    __syncthreads();

    if (wave == 0) {
        int r = 0;
#pragma unroll
        for (int pp = 0; pp < 16; ++pp) r += pc[pp][lane];
        q_sorted[b * N + r] = ord2f((unsigned int)(myKey >> 32));
        ordidx[b * N + r] = (unsigned int)(myKey & 0xFFFFFFFFu);
    }
}

// ===========================================================================
// K2: one block per (batch, feature). Full suffix/prefix scans over sorted
// rows in LDS, then per original row i: p = lower_bound(q_sorted, -k_i),
//   out[b,f,i] = (c1*SUF1[p] + c2*PRE2[p]) / (c1*SUFD[p] + c2*PRED[p])
// with c1 = e^{u-M}, c2 = e^{0.2u-M}, u = k_i + Qmax, M = max(u, 0.2u),
// E1[t] = e^{q_t - Qmax}, E2[t] = e^{0.2(q_t - Qmax)}.
// Scan: thread-local 4-elem scans -> wave Hillis-Steele (shfl) -> wave bases
// by thread 0. SUF1/SUFD scanned from the top (largest terms first).
// LDS: qsl 16K + 4 arrays (N+4) floats = ~82 KB (fine on gfx950's 160 KB).
// ===========================================================================
__global__ __launch_bounds__(1024) void feat_kernel(
        const float* __restrict__ x, const float* __restrict__ karr,
        const float* __restrict__ q_sorted,
        const unsigned int* __restrict__ ordidx, float* __restrict__ out) {
    __shared__ __align__(16) float qsl[N];
    __shared__ __align__(16) float SUF1[N + 4], PRE2[N + 4];
    __shared__ __align__(16) float SUFD[N + 4], PRED[N + 4];
    __shared__ float wt1[16], wt2[16], wtd1[16], wtd2[16];
    __shared__ float wb1[16], wb2[16], wbd1[16], wbd2[16];
    const int bid = blockIdx.x;
    const int b = bid >> 6, f = bid & 63;
    const int tid = threadIdx.x;
    const int wave = tid >> 6, lane = tid & 63;
    const int t0 = tid << 2;
    const float* qsb = q_sorted + b * N;
    const float Qmax = qsb[N - 1];

    // per-thread 4 sorted rows: E1,E2 and gathered feature column
    float4 qv = *(const float4*)(qsb + t0);
    uint4 iv = *(const uint4*)(ordidx + b * N + t0);
    *(float4*)(qsl + t0) = qv;
    float qa[4] = {qv.x, qv.y, qv.z, qv.w};
    unsigned ia[4] = {iv.x, iv.y, iv.z, iv.w};
    float e1[4], e2[4], w1[4], w2[4];
    const float* xbf = x + (size_t)b * N * F + f;
#pragma unroll
    for (int r = 0; r < 4; ++r) {
        float d = qa[r] - Qmax;
        e1[r] = __expf(d);
        e2[r] = __expf(0.2f * d);
        float xf = xbf[(size_t)ia[r] * F];     // L2-resident gather
        w1[r] = e1[r] * xf;
        w2[r] = e2[r] * xf;
    }

    // thread-local: exclusive prefix (w2,e2), inclusive suffix (w1,e1)
    float lp2_0 = 0.f, lp2_1 = w2[0], lp2_2 = lp2_1 + w2[1], lp2_3 = lp2_2 + w2[2];
    float T2 = lp2_3 + w2[3];
    float lpd_0 = 0.f, lpd_1 = e2[0], lpd_2 = lpd_1 + e2[1], lpd_3 = lpd_2 + e2[2];
    float TD2 = lpd_3 + e2[3];
    float ls1_3 = w1[3], ls1_2 = w1[2] + ls1_3, ls1_1 = w1[1] + ls1_2, ls1_0 = w1[0] + ls1_1;
    float T1 = ls1_0;
    float lsd_3 = e1[3], lsd_2 = e1[2] + lsd_3, lsd_1 = e1[1] + lsd_2, lsd_0 = e1[0] + lsd_1;
    float TD1 = lsd_0;

    // wave-level inclusive prefix (up) and inclusive suffix (down)
    float ip2 = T2, ipd2 = TD2;
#pragma unroll
    for (int d = 1; d < 64; d <<= 1) {
        float n1 = __shfl_up(ip2, d, 64);
        float n2 = __shfl_up(ipd2, d, 64);
        if (lane >= d) { ip2 += n1; ipd2 += n2; }
    }
    float is1 = T1, isd1 = TD1;
#pragma unroll
    for (int d = 1; d < 64; d <<= 1) {
        float n1 = __shfl_down(is1, d, 64);
        float n2 = __shfl_down(isd1, d, 64);
        if (lane + d < 64) { is1 += n1; isd1 += n2; }
    }
    if (lane == 63) { wt2[wave] = ip2; wtd2[wave] = ipd2; }
    if (lane == 0)  { wt1[wave] = is1; wtd1[wave] = isd1; }
    __syncthreads();
    if (tid == 0) {
        float a2 = 0.f, ad2 = 0.f;
#pragma unroll
        for (int w = 0; w < 16; ++w) {
            wb2[w] = a2; a2 += wt2[w];
            wbd2[w] = ad2; ad2 += wtd2[w];
        }
        PRE2[N] = a2; PRED[N] = ad2;
        float a1 = 0.f, ad1 = 0.f;
#pragma unroll
        for (int w = 15; w >= 0; --w) {
            wb1[w] = a1; a1 += wt1[w];
            wbd1[w] = ad1; ad1 += wtd1[w];
        }
        SUF1[N] = 0.f; SUFD[N] = 0.f;
    }
    __syncthreads();
    float bp2 = wb2[wave] + (ip2 - T2);        // exclusive prefix base
    float bpd = wbd2[wave] + (ipd2 - TD2);
    float bs1 = wb1[wave] + (is1 - T1);        // suffix base (strictly after)
    float bsd = wbd1[wave] + (isd1 - TD1);
    float4 o;
    o.x = bp2 + lp2_0; o.y = bp2 + lp2_1; o.z = bp2 + lp2_2; o.w = bp2 + lp2_3;
    *(float4*)(PRE2 + t0) = o;
    o.x = bpd + lpd_0; o.y = bpd + lpd_1; o.z = bpd + lpd_2; o.w = bpd + lpd_3;
    *(float4*)(PRED + t0) = o;
    o.x = bs1 + ls1_0; o.y = bs1 + ls1_1; o.z = bs1 + ls1_2; o.w = bs1 + ls1_3;
    *(float4*)(SUF1 + t0) = o;
    o.x = bsd + lsd_0; o.y = bsd + lsd_1; o.z = bsd + lsd_2; o.w = bsd + lsd_3;
    *(float4*)(SUFD + t0) = o;
    __syncthreads();

    // lookup: 4 original rows per thread, binary search p, combine, write f4
    float4 kv = *(const float4*)(karr + b * N + t0);
    float ka[4] = {kv.x, kv.y, kv.z, kv.w};
    float ra[4];
#pragma unroll
    for (int r = 0; r < 4; ++r) {
        float kk = ka[r];
        float theta = -kk;
        int lo = 0, hi = N;
#pragma unroll
        for (int s = 0; s < 12; ++s) {
            int mid = (lo + hi) >> 1;
            if (qsl[mid] < theta) lo = mid + 1; else hi = mid;
        }
        float u = kk + Qmax;
        float M = fmaxf(u, 0.2f * u);
        float c1 = __expf(u - M);
        float c2 = __expf(0.2f * u - M);
        float num = c1 * SUF1[lo] + c2 * PRE2[lo];
        float den = c1 * SUFD[lo] + c2 * PRED[lo];
        ra[r] = num / den;
    }
    float4 res; res.x = ra[0]; res.y = ra[1]; res.z = ra[2]; res.w = ra[3];
    *(float4*)(out + ((size_t)(b * F + f)) * N + t0) = res;
}

// ---------------------------------------------------------------------------
extern "C" void kernel_launch(void* const* d_in, const int* in_sizes, int n_in,
                              void* d_out, int out_size, void* d_ws, size_t ws_size,
                              hipStream_t stream) {
    const float* x  = (const float*)d_in[0];
    const float* wk = (const float*)d_in[1];
    const float* wq = (const float*)d_in[2];
    float* out = (float*)d_out;

    // ws layout (floats): karr[BZ*N] | q_sorted[BZ*N] | ordidx(u32)[BZ*N]
    float* ws = (float*)d_ws;
    float* karr = ws;
    float* q_sorted = ws + BZ * N;
    unsigned int* ordidx = (unsigned int*)(ws + 2 * BZ * N);

    rank_kernel<<<BZ * 64, 1024, 0, stream>>>(x, wk, wq, karr, q_sorted, ordidx);
    feat_kernel<<<BZ * F, 1024, 0, stream>>>(x, karr, q_sorted, ordidx, out);
}

// Round 4
// 78.487 us; speedup vs baseline: 2.3170x; 1.4306x over previous
//
#include <hip/hip_runtime.h>

#define N 4096
#define F 64
#define BZ 4
// NEG_SLOPE = 0.2 hardcoded below.

// order-preserving float <-> uint32 mapping
__device__ __forceinline__ unsigned int f2ord(float f) {
    unsigned int u = __float_as_uint(f);
    return (u & 0x80000000u) ? ~u : (u ^ 0x80000000u);
}
__device__ __forceinline__ float ord2f(unsigned int v) {
    unsigned int b = (v & 0x80000000u) ? (v ^ 0x80000000u) : ~v;
    return __uint_as_float(b);
}

// ===========================================================================
// K1: grid BZ*64, block 1024. Block = (batch, chunk of 64 rows).
// Computes k/q dots for its own 64 rows (NO redundancy) and writes a
// transposed copy xT[b][f][i] so K3's gather is within a 16 KB L1-resident
// row. Thread t: row = wave*4 + (lane>>4), feature-quad = lane&15.
// ===========================================================================
__global__ __launch_bounds__(1024) void dot_kernel(
        const float* __restrict__ x, const float* __restrict__ wk,
        const float* __restrict__ wq, float* __restrict__ karr,
        unsigned long long* __restrict__ qkey, float* __restrict__ xT) {
    __shared__ float tile[64][68];            // [f][r], stride 68 keeps f4 align
    const int b = blockIdx.x >> 6, chunk = blockIdx.x & 63;
    const int tid = threadIdx.x;
    const int wave = tid >> 6, lane = tid & 63;
    const int sub = lane >> 4, fq = lane & 15;
    const int lr = wave * 4 + sub;            // local row 0..63
    const int grow = chunk * 64 + lr;         // global row
    const int f0 = fq << 2;

    float4 xv = *(const float4*)(x + ((size_t)b * N + grow) * F + f0);
    float4 k4 = *(const float4*)(wk + f0);
    float4 q4 = *(const float4*)(wq + f0);
    float kk = xv.x * k4.x + xv.y * k4.y + xv.z * k4.z + xv.w * k4.w;
    float qq = xv.x * q4.x + xv.y * q4.y + xv.z * q4.z + xv.w * q4.w;
#pragma unroll
    for (int off = 1; off <= 8; off <<= 1) {
        kk += __shfl_xor(kk, off, 16);
        qq += __shfl_xor(qq, off, 16);
    }
    if (fq == 0) {
        karr[b * N + grow] = kk;
        qkey[b * N + grow] = ((unsigned long long)f2ord(qq) << 32)
                           | (unsigned int)grow;
    }
    tile[f0 + 0][lr] = xv.x;
    tile[f0 + 1][lr] = xv.y;
    tile[f0 + 2][lr] = xv.z;
    tile[f0 + 3][lr] = xv.w;
    __syncthreads();
    const int fo = wave * 4 + sub;            // feature this thread outputs
    float4 ov = *(const float4*)(&tile[fo][fq << 2]);
    *(float4*)(xT + ((size_t)(b * F + fo)) * N + chunk * 64 + (fq << 2)) = ov;
}

// ===========================================================================
// K2: grid BZ*64, block 1024. Rank count (strict total order on u64 keys)
// PLUS fused boundary count p_i = #{j : q_j < -k_i} (replaces K3's binary
// search). Wave-uniform broadcast LDS reads -> VALU-bound inner loop.
// ===========================================================================
__global__ __launch_bounds__(1024) void rank_kernel(
        const unsigned long long* __restrict__ qkey,
        const float* __restrict__ karr,
        float* __restrict__ q_sorted, unsigned int* __restrict__ ordidx,
        int* __restrict__ pA) {
    __shared__ __align__(16) unsigned long long qs[N];   // 32 KB
    __shared__ unsigned short pc[16][64];
    __shared__ unsigned short pc2[16][64];
    const int b = blockIdx.x >> 6, chunk = blockIdx.x & 63;
    const int tid = threadIdx.x;
    const int wave = tid >> 6, lane = tid & 63;
    const unsigned long long* qb = qkey + b * N;
    for (int t = tid; t < N; t += 1024) qs[t] = qb[t];
    const float kk = karr[b * N + chunk * 64 + lane];
    const unsigned int thetaOrd = f2ord(-kk);
    __syncthreads();

    const unsigned long long myKey = qs[chunk * 64 + lane];
    int cnt = 0, cnt2 = 0;
    const ulonglong2* q2 = (const ulonglong2*)qs;
    const int s0 = wave * 128;                // ulonglong2 units
#pragma unroll 8
    for (int t2 = 0; t2 < 128; ++t2) {
        ulonglong2 v = q2[s0 + t2];           // wave-uniform broadcast read
        cnt  += (int)(v.x < myKey) + (int)(v.y < myKey);
        cnt2 += (int)((unsigned int)(v.x >> 32) < thetaOrd)
              + (int)((unsigned int)(v.y >> 32) < thetaOrd);
    }
    pc[wave][lane]  = (unsigned short)cnt;
    pc2[wave][lane] = (unsigned short)cnt2;
    __syncthreads();

    if (wave == 0) {
        int r = 0, p = 0;
#pragma unroll
        for (int w = 0; w < 16; ++w) { r += pc[w][lane]; p += pc2[w][lane]; }
        q_sorted[b * N + r] = ord2f((unsigned int)(myKey >> 32));
        ordidx[b * N + r] = (unsigned int)(myKey & 0xFFFFFFFFu);
        pA[b * N + chunk * 64 + lane] = p;
    }
}

// ===========================================================================
// K3: one block per (batch, feature). Full suffix/prefix scans over sorted
// rows in LDS, then per original row i (p_i precomputed in K2):
//   out[b,f,i] = (c1*SUF1[p] + c2*PRE2[p]) / (c1*SUFD[p] + c2*PRED[p])
// with c1 = e^{u-M}, c2 = e^{0.2u-M}, u = k_i + Qmax, M = max(u, 0.2u),
// E1[t] = e^{q_t - Qmax}, E2[t] = e^{0.2(q_t - Qmax)}.
// x gather reads this block's own 16 KB row of xT (L1-resident).
// LDS: 4 arrays (N+4) floats = ~65.7 KB.
// ===========================================================================
__global__ __launch_bounds__(1024) void feat_kernel(
        const float* __restrict__ xT, const float* __restrict__ karr,
        const float* __restrict__ q_sorted,
        const unsigned int* __restrict__ ordidx,
        const int* __restrict__ pA, float* __restrict__ out) {
    __shared__ __align__(16) float SUF1[N + 4], PRE2[N + 4];
    __shared__ __align__(16) float SUFD[N + 4], PRED[N + 4];
    __shared__ float wt1[16], wt2[16], wtd1[16], wtd2[16];
    __shared__ float wb1[16], wb2[16], wbd1[16], wbd2[16];
    const int bid = blockIdx.x;
    const int b = bid >> 6, f = bid & 63;
    const int tid = threadIdx.x;
    const int wave = tid >> 6, lane = tid & 63;
    const int t0 = tid << 2;
    const float* qsb = q_sorted + b * N;
    const float Qmax = qsb[N - 1];

    // per-thread 4 sorted rows: E1,E2 and gathered feature column
    float4 qv = *(const float4*)(qsb + t0);
    uint4 iv = *(const uint4*)(ordidx + b * N + t0);
    float qa[4] = {qv.x, qv.y, qv.z, qv.w};
    unsigned ia[4] = {iv.x, iv.y, iv.z, iv.w};
    float e1[4], e2[4], w1[4], w2[4];
    const float* xrow = xT + (size_t)(b * F + f) * N;   // 16 KB, L1-resident
#pragma unroll
    for (int r = 0; r < 4; ++r) {
        float d = qa[r] - Qmax;
        e1[r] = __expf(d);
        e2[r] = __expf(0.2f * d);
        float xf = xrow[ia[r]];
        w1[r] = e1[r] * xf;
        w2[r] = e2[r] * xf;
    }

    // thread-local: exclusive prefix (w2,e2), inclusive suffix (w1,e1)
    float lp2_0 = 0.f, lp2_1 = w2[0], lp2_2 = lp2_1 + w2[1], lp2_3 = lp2_2 + w2[2];
    float T2 = lp2_3 + w2[3];
    float lpd_0 = 0.f, lpd_1 = e2[0], lpd_2 = lpd_1 + e2[1], lpd_3 = lpd_2 + e2[2];
    float TD2 = lpd_3 + e2[3];
    float ls1_3 = w1[3], ls1_2 = w1[2] + ls1_3, ls1_1 = w1[1] + ls1_2, ls1_0 = w1[0] + ls1_1;
    float T1 = ls1_0;
    float lsd_3 = e1[3], lsd_2 = e1[2] + lsd_3, lsd_1 = e1[1] + lsd_2, lsd_0 = e1[0] + lsd_1;
    float TD1 = lsd_0;

    // wave-level inclusive prefix (up) and inclusive suffix (down)
    float ip2 = T2, ipd2 = TD2;
#pragma unroll
    for (int d = 1; d < 64; d <<= 1) {
        float n1 = __shfl_up(ip2, d, 64);
        float n2 = __shfl_up(ipd2, d, 64);
        if (lane >= d) { ip2 += n1; ipd2 += n2; }
    }
    float is1 = T1, isd1 = TD1;
#pragma unroll
    for (int d = 1; d < 64; d <<= 1) {
        float n1 = __shfl_down(is1, d, 64);
        float n2 = __shfl_down(isd1, d, 64);
        if (lane + d < 64) { is1 += n1; isd1 += n2; }
    }
    if (lane == 63) { wt2[wave] = ip2; wtd2[wave] = ipd2; }
    if (lane == 0)  { wt1[wave] = is1; wtd1[wave] = isd1; }
    __syncthreads();
    if (tid == 0) {
        float a2 = 0.f, ad2 = 0.f;
#pragma unroll
        for (int w = 0; w < 16; ++w) {
            wb2[w] = a2; a2 += wt2[w];
            wbd2[w] = ad2; ad2 += wtd2[w];
        }
        PRE2[N] = a2; PRED[N] = ad2;
        float a1 = 0.f, ad1 = 0.f;
#pragma unroll
        for (int w = 15; w >= 0; --w) {
            wb1[w] = a1; a1 += wt1[w];
            wbd1[w] = ad1; ad1 += wtd1[w];
        }
        SUF1[N] = 0.f; SUFD[N] = 0.f;
    }
    __syncthreads();
    float bp2 = wb2[wave] + (ip2 - T2);        // exclusive prefix base
    float bpd = wbd2[wave] + (ipd2 - TD2);
    float bs1 = wb1[wave] + (is1 - T1);        // suffix base (strictly after)
    float bsd = wbd1[wave] + (isd1 - TD1);
    float4 o;
    o.x = bp2 + lp2_0; o.y = bp2 + lp2_1; o.z = bp2 + lp2_2; o.w = bp2 + lp2_3;
    *(float4*)(PRE2 + t0) = o;
    o.x = bpd + lpd_0; o.y = bpd + lpd_1; o.z = bpd + lpd_2; o.w = bpd + lpd_3;
    *(float4*)(PRED + t0) = o;
    o.x = bs1 + ls1_0; o.y = bs1 + ls1_1; o.z = bs1 + ls1_2; o.w = bs1 + ls1_3;
    *(float4*)(SUF1 + t0) = o;
    o.x = bsd + lsd_0; o.y = bsd + lsd_1; o.z = bsd + lsd_2; o.w = bsd + lsd_3;
    *(float4*)(SUFD + t0) = o;
    __syncthreads();

    // lookup: 4 original rows per thread (p precomputed), combine, write f4
    float4 kv = *(const float4*)(karr + b * N + t0);
    int4 pv = *(const int4*)(pA + b * N + t0);
    float ka[4] = {kv.x, kv.y, kv.z, kv.w};
    int pa[4] = {pv.x, pv.y, pv.z, pv.w};
    float ra[4];
#pragma unroll
    for (int r = 0; r < 4; ++r) {
        float kk = ka[r];
        int p = pa[r];
        float u = kk + Qmax;
        float M = fmaxf(u, 0.2f * u);
        float c1 = __expf(u - M);
        float c2 = __expf(0.2f * u - M);
        float num = c1 * SUF1[p] + c2 * PRE2[p];
        float den = c1 * SUFD[p] + c2 * PRED[p];
        ra[r] = num / den;
    }
    float4 res; res.x = ra[0]; res.y = ra[1]; res.z = ra[2]; res.w = ra[3];
    *(float4*)(out + ((size_t)(b * F + f)) * N + t0) = res;
}

// ---------------------------------------------------------------------------
extern "C" void kernel_launch(void* const* d_in, const int* in_sizes, int n_in,
                              void* d_out, int out_size, void* d_ws, size_t ws_size,
                              hipStream_t stream) {
    const float* x  = (const float*)d_in[0];
    const float* wk = (const float*)d_in[1];
    const float* wq = (const float*)d_in[2];
    float* out = (float*)d_out;

    // ws layout (floats): karr[BZ*N] | qkey(u64)[BZ*N] (=2*BZ*N floats) |
    //   q_sorted[BZ*N] | ordidx(u32)[BZ*N] | pA(i32)[BZ*N] | xT[BZ*F*N]
    float* ws = (float*)d_ws;
    float* karr = ws;
    unsigned long long* qkey = (unsigned long long*)(ws + BZ * N);
    float* q_sorted = ws + 3 * BZ * N;
    unsigned int* ordidx = (unsigned int*)(ws + 4 * BZ * N);
    int* pA = (int*)(ws + 5 * BZ * N);
    float* xT = ws + 6 * BZ * N;

    dot_kernel<<<BZ * 64, 1024, 0, stream>>>(x, wk, wq, karr, qkey, xT);
    rank_kernel<<<BZ * 64, 1024, 0, stream>>>(qkey, karr, q_sorted, ordidx, pA);
    feat_kernel<<<BZ * F, 1024, 0, stream>>>(xT, karr, q_sorted, ordidx, pA, out);
}